// Round 1
// baseline (1468.687 us; speedup 1.0000x reference)
//
#include <hip/hip_runtime.h>
#include <math.h>

#define BB 64
#define TT 4096
#define CC 64

constexpr int L0v = 2048, U0v = 3069, V0v = 1535, P0v = 2048;
constexpr int L1v = 1024, U1v = 1533, V1v = 767,  P1v = 1024;
constexpr int OUTL = 6144;
constexpr long NTOT = (long)BB * TT * CC;

// ---------------- global stats (mean, std ddof=1) ----------------
__global__ __launch_bounds__(256) void stats_partial(const float* __restrict__ x,
                                                     double* __restrict__ part) {
  __shared__ double s1[256], s2[256];
  double a = 0, q = 0;
  for (long i = (long)blockIdx.x * 256 + threadIdx.x; i < NTOT; i += (long)gridDim.x * 256) {
    double v = (double)x[i];
    a += v; q += v * v;
  }
  s1[threadIdx.x] = a; s2[threadIdx.x] = q;
  __syncthreads();
  for (int s = 128; s > 0; s >>= 1) {
    if (threadIdx.x < s) { s1[threadIdx.x] += s1[threadIdx.x + s]; s2[threadIdx.x] += s2[threadIdx.x + s]; }
    __syncthreads();
  }
  if (threadIdx.x == 0) { part[blockIdx.x * 2] = s1[0]; part[blockIdx.x * 2 + 1] = s2[0]; }
}

__global__ __launch_bounds__(256) void stats_final(const double* __restrict__ part,
                                                   double* __restrict__ stats) {
  __shared__ double s1[256], s2[256];
  double a = 0, q = 0;
  for (int i = threadIdx.x; i < 1024; i += 256) { a += part[2 * i]; q += part[2 * i + 1]; }
  s1[threadIdx.x] = a; s2[threadIdx.x] = q;
  __syncthreads();
  for (int s = 128; s > 0; s >>= 1) {
    if (threadIdx.x < s) { s1[threadIdx.x] += s1[threadIdx.x + s]; s2[threadIdx.x] += s2[threadIdx.x + s]; }
    __syncthreads();
  }
  if (threadIdx.x == 0) {
    double n = (double)NTOT;
    double mean = s1[0] / n;
    double var = (s2[0] - s1[0] * s1[0] / n) / (n - 1.0);
    double sd = sqrt(var);
    stats[0] = mean; stats[1] = sd;
    stats[2] = 0.8 / mean;   // coef for out_mean branch
    stats[3] = 0.8 / sd;     // coef for out_std branch
  }
}

// ---------------- weight norm: w[o,i,k] = g[o]/||v[o]|| * v[o,i,k] ----------------
__global__ __launch_bounds__(256) void weight_norm(const float* __restrict__ v,
                                                   const float* __restrict__ g,
                                                   float* __restrict__ w) {
  int o = blockIdx.x;
  __shared__ float red[256];
  __shared__ float scale;
  int tid = threadIdx.x;
  float vv = (tid < 192) ? v[o * 192 + tid] : 0.f;
  red[tid] = vv * vv;
  __syncthreads();
  for (int s = 128; s > 0; s >>= 1) {
    if (tid < s) red[tid] += red[tid + s];
    __syncthreads();
  }
  if (tid == 0) scale = g[o] / sqrtf(red[0]);
  __syncthreads();
  if (tid < 192) w[o * 192 + tid] = scale * vv;
}

// ---------------- closed-form index helpers ----------------
// _dpadding_indices closed form (verified against python simulation):
//  lvl0: brk=1536 dup=1024 sub=513 ; lvl1: brk=768 dup=512 sub=257
__device__ __host__ inline int pad_idx(int p, int brk, int dup, int sub) {
  if (p < brk) { int q = p / 3; int r = p - 3 * q; return 2 * q + (r == 2 ? 1 : 0); }
  if (p < brk + 2) return dup;
  return p - sub;
}

// sew-up composed index: returns s into concat([C1(2048), L0(4096)]).
// Pattern: k=0 -> b0, k=1 -> a0, then 455 cycles of 12 (9 b, 3 a), then a-tail.
__device__ inline int fmap_code(int k) {
  if (k == 0) return 2048 + 0;
  if (k == 1) return 0;
  if (k < 5462) {
    int m = k - 2;
    int c = m / 12;
    int j = m - 12 * c;
    if (j <= 3)  return 2048 + (1 + 9 * c + j);
    if (j == 4)  return 1 + 3 * c;
    if (j <= 8)  return 2048 + (9 * c + j);      // == 5+9c .. 8+9c
    if (j == 9)  return 2 + 3 * c;
    if (j == 10) return 2048 + (9 + 9 * c);
    return 3 + 3 * c;                             // j == 11
  }
  return k - 4096;  // a-tail: a(1366..2047)
}

// ---------------- fused conv (wnorm, stride2, dil3) + bias + maxpool(3,s2,p1) + elu + gauss ----
// y1[b,o,v] = exp(-elu(maxpool(conv(joined)+bias))^2/2)
__global__ __launch_bounds__(256) void conv_pool(
    const float* __restrict__ x, const float* __restrict__ w,
    const float* __restrict__ cbias, const double* __restrict__ stats,
    float* __restrict__ y1, int L, int U, int V, int mult, int off1) {
  const int b = blockIdx.x;
  const int v0 = blockIdx.y * 32;
  const int tid = threadIdx.x;
  const float inv_mean = (float)stats[2];
  const float inv_std = (float)stats[3];

  const int vend = min(v0 + 32, V);
  const int u_lo = 2 * v0 - 1;
  const int u_hi = 2 * vend - 1;
  const int NU = u_hi - u_lo + 1;                  // <= 65
  const int uv_lo = max(u_lo, 0);
  const int uv_hi = min(u_hi, U - 1);
  const int t_lo = (2 * uv_lo) / 3;
  int t_hi = (2 * uv_hi + 6) / 3;
  if (t_hi > L - 1) t_hi = L - 1;
  const int tcnt = t_hi - t_lo + 1;                // <= 46

  __shared__ float X0[46][CC + 1];
  __shared__ float X1[46][CC + 1];
  __shared__ float cbf[64][66];

  const long xbase = (long)b * TT * CC;
  for (int idx = tid; idx < tcnt * CC; idx += 256) {
    int tr = idx >> 6, c = idx & 63;
    int t = t_lo + tr;
    X0[tr][c] = x[xbase + (long)(mult * t) * CC + c];
    X1[tr][c] = x[xbase + (long)(mult * t + off1) * CC + c];
  }
  __syncthreads();

  for (int idx = tid; idx < 64 * NU; idx += 256) {
    int o = idx / NU, ul = idx - o * NU;
    int u = u_lo + ul;
    float acc = -INFINITY;
    if (u >= 0 && u < U) {
      acc = cbias[o];
      int t0 = (2 * u) / 3;
      int r = 2 * u - 3 * t0;       // same phase for all 3 taps (stride2/dil3)
      int tr = t0 - t_lo;
      const float* wr = w + o * 192;
      if (r == 1) {
        for (int i = 0; i < CC; i++) {
          acc += wr[i * 3] * X0[tr][i] + wr[i * 3 + 1] * X0[tr + 1][i] + wr[i * 3 + 2] * X0[tr + 2][i];
        }
      } else {
        float a = (r == 0) ? inv_mean : inv_std;
        for (int i = 0; i < CC; i++) {
          float j0 = fmaf(a, X1[tr][i],     0.2f * X0[tr][i]);
          float j1 = fmaf(a, X1[tr + 1][i], 0.2f * X0[tr + 1][i]);
          float j2 = fmaf(a, X1[tr + 2][i], 0.2f * X0[tr + 2][i]);
          acc += wr[i * 3] * j0 + wr[i * 3 + 1] * j1 + wr[i * 3 + 2] * j2;
        }
      }
    }
    cbf[o][ul] = acc;
  }
  __syncthreads();

  const int vl = tid & 31, cg = tid >> 5;
  const int v = v0 + vl;
  if (v < vend) {
    for (int o = cg; o < 64; o += 8) {
      float m = -INFINITY;
#pragma unroll
      for (int d = 0; d < 3; d++) {
        int u = 2 * v - 1 + d;
        if (u >= 0 && u < U) m = fmaxf(m, cbf[o][u - u_lo]);
      }
      float e = (m > 0.f) ? m : (expf(m) - 1.f);
      y1[((long)(b * 64 + o)) * V + v] = expf(-0.5f * e * e);
    }
  }
}

// ---------------- batchnorm statistics over (B, P) per channel (on dpad-gathered y1) ----
__global__ __launch_bounds__(256) void bn_stats(const float* __restrict__ y1,
                                                float* __restrict__ bnp,
                                                int V, int P, int brk, int dup, int sub) {
  const int c = blockIdx.x;
  __shared__ double s1[256], s2[256];
  double a = 0, q = 0;
  for (int idx = threadIdx.x; idx < BB * P; idx += 256) {
    int b = idx / P, p = idx - b * P;
    float v = y1[((long)(b * 64 + c)) * V + pad_idx(p, brk, dup, sub)];
    a += v; q += (double)v * (double)v;
  }
  s1[threadIdx.x] = a; s2[threadIdx.x] = q;
  __syncthreads();
  for (int s = 128; s > 0; s >>= 1) {
    if (threadIdx.x < s) { s1[threadIdx.x] += s1[threadIdx.x + s]; s2[threadIdx.x] += s2[threadIdx.x + s]; }
    __syncthreads();
  }
  if (threadIdx.x == 0) {
    double n = (double)BB * P;
    double mu = s1[0] / n;
    double var = s2[0] / n - mu * mu;   // population (biased), as reference
    bnp[2 * c] = (float)mu;
    bnp[2 * c + 1] = 1.0f / sqrtf((float)var + 1e-5f);
  }
}

// ---------------- out = xn + elu(bn(y_pad)) ----------------
__global__ __launch_bounds__(256) void finalize_out(
    const float* __restrict__ x, const float* __restrict__ y1,
    const float* __restrict__ bnp, const float* __restrict__ gamma,
    const float* __restrict__ beta, float* __restrict__ outn,
    int V, int P, int mult, int off1, int brk, int dup, int sub) {
  const int b = blockIdx.x;
  const int p0 = blockIdx.y * 32;
  const int tid = threadIdx.x;
  __shared__ float XT[32][CC + 1];
  const long xbase = (long)b * TT * CC;
  {
    int c = tid & 63;
    for (int pr = tid >> 6; pr < 32; pr += 4)
      XT[pr][c] = x[xbase + (long)(mult * (p0 + pr) + off1) * CC + c];
  }
  __syncthreads();
  const int vl = tid & 31, cg = tid >> 5;
  const int p = p0 + vl;
  const int pi = pad_idx(p, brk, dup, sub);
  for (int c = cg; c < 64; c += 8) {
    float yv = y1[((long)(b * 64 + c)) * V + pi];
    float z = gamma[c] * (yv - bnp[2 * c]) * bnp[2 * c + 1] + beta[c];
    float e = (z > 0.f) ? z : (expf(z) - 1.f);
    outn[((long)(b * 64 + c)) * P + p] = XT[vl][c] + e;
  }
}

// ---------------- final sew-up gather ----------------
__global__ __launch_bounds__(256) void final_gather(
    const float* __restrict__ x, const float* __restrict__ out0,
    const float* __restrict__ out1, float* __restrict__ out) {
  long idx = (long)blockIdx.x * 256 + threadIdx.x;
  if (idx >= (long)BB * CC * OUTL) return;
  int k = (int)(idx % OUTL);
  long bc = idx / OUTL;
  int c = (int)(bc & 63);
  long b = bc >> 6;
  int s = fmap_code(k);
  float v;
  if (s < 2048) {                 // C1 (level-1 pre-sew, length 2048)
    if ((s & 1) == 0) v = x[b * TT * CC + (long)(2 * s) * CC + c];   // nodes[2][s/2] = xT[2s]
    else              v = out1[bc * P1v + (s >> 1)];
  } else {                        // L0 (level-0 output, length 4096)
    int p = s - 2048;
    if ((p & 1) == 0) v = x[b * TT * CC + (long)p * CC + c];         // nodes[0][p/2] = xT[p]
    else              v = out0[bc * P0v + (p >> 1)];
  }
  out[idx] = v;
}

extern "C" void kernel_launch(void* const* d_in, const int* in_sizes, int n_in,
                              void* d_out, int out_size, void* d_ws, size_t ws_size,
                              hipStream_t stream) {
  const float* x   = (const float*)d_in[0];
  const float* cv  = (const float*)d_in[1];
  const float* cg  = (const float*)d_in[2];
  const float* cb  = (const float*)d_in[3];
  const float* gam = (const float*)d_in[4];
  const float* bet = (const float*)d_in[5];
  float* out = (float*)d_out;

  char* ws = (char*)d_ws;
  size_t cur = 0;
  auto alloc = [&](size_t bytes) -> char* {
    char* p = ws + cur;
    cur = (cur + bytes + 255) & ~(size_t)255;
    return p;
  };
  double* part  = (double*)alloc(1024 * 2 * sizeof(double));
  double* stats = (double*)alloc(4 * sizeof(double));
  float*  w     = (float*)alloc(64 * 192 * sizeof(float));
  float*  bnp0  = (float*)alloc(128 * sizeof(float));
  float*  bnp1  = (float*)alloc(128 * sizeof(float));
  float*  y10   = (float*)alloc((size_t)4096 * V0v * sizeof(float));
  float*  y11   = (float*)alloc((size_t)4096 * V1v * sizeof(float));
  float*  o0    = (float*)alloc((size_t)4096 * P0v * sizeof(float));
  float*  o1    = (float*)alloc((size_t)4096 * P1v * sizeof(float));

  stats_partial<<<1024, 256, 0, stream>>>(x, part);
  stats_final<<<1, 256, 0, stream>>>(part, stats);
  weight_norm<<<64, 256, 0, stream>>>(cv, cg, w);

  conv_pool<<<dim3(64, 48), 256, 0, stream>>>(x, w, cb, stats, y10, L0v, U0v, V0v, 2, 1);
  conv_pool<<<dim3(64, 24), 256, 0, stream>>>(x, w, cb, stats, y11, L1v, U1v, V1v, 4, 3);

  bn_stats<<<64, 256, 0, stream>>>(y10, bnp0, V0v, P0v, 1536, 1024, 513);
  bn_stats<<<64, 256, 0, stream>>>(y11, bnp1, V1v, P1v, 768, 512, 257);

  finalize_out<<<dim3(64, 64), 256, 0, stream>>>(x, y10, bnp0, gam, bet, o0, V0v, P0v, 2, 1, 1536, 1024, 513);
  finalize_out<<<dim3(64, 32), 256, 0, stream>>>(x, y11, bnp1, gam, bet, o1, V1v, P1v, 4, 3, 768, 512, 257);

  long ntot_out = (long)BB * CC * OUTL;
  final_gather<<<(int)((ntot_out + 255) / 256), 256, 0, stream>>>(x, o0, o1, out);
}

// Round 2
// 781.856 us; speedup vs baseline: 1.8785x; 1.8785x over previous
//
#include <hip/hip_runtime.h>
#include <math.h>

#define BB 64
#define TT 4096
#define CC 64

constexpr int L0v = 2048, U0v = 3069, V0v = 1535, P0v = 2048;
constexpr int L1v = 1024, U1v = 1533, V1v = 767,  P1v = 1024;
constexpr int OUTL = 6144;
constexpr long NTOT = (long)BB * TT * CC;

// ---------------- global stats (mean, std ddof=1) ----------------
__global__ __launch_bounds__(256) void stats_partial(const float* __restrict__ x,
                                                     double* __restrict__ part) {
  __shared__ double s1[256], s2[256];
  double a = 0, q = 0;
  for (long i = (long)blockIdx.x * 256 + threadIdx.x; i < NTOT; i += (long)gridDim.x * 256) {
    double v = (double)x[i];
    a += v; q += v * v;
  }
  s1[threadIdx.x] = a; s2[threadIdx.x] = q;
  __syncthreads();
  for (int s = 128; s > 0; s >>= 1) {
    if (threadIdx.x < s) { s1[threadIdx.x] += s1[threadIdx.x + s]; s2[threadIdx.x] += s2[threadIdx.x + s]; }
    __syncthreads();
  }
  if (threadIdx.x == 0) { part[blockIdx.x * 2] = s1[0]; part[blockIdx.x * 2 + 1] = s2[0]; }
}

__global__ __launch_bounds__(256) void stats_final(const double* __restrict__ part,
                                                   double* __restrict__ stats) {
  __shared__ double s1[256], s2[256];
  double a = 0, q = 0;
  for (int i = threadIdx.x; i < 1024; i += 256) { a += part[2 * i]; q += part[2 * i + 1]; }
  s1[threadIdx.x] = a; s2[threadIdx.x] = q;
  __syncthreads();
  for (int s = 128; s > 0; s >>= 1) {
    if (threadIdx.x < s) { s1[threadIdx.x] += s1[threadIdx.x + s]; s2[threadIdx.x] += s2[threadIdx.x + s]; }
    __syncthreads();
  }
  if (threadIdx.x == 0) {
    double n = (double)NTOT;
    double mean = s1[0] / n;
    double var = (s2[0] - s1[0] * s1[0] / n) / (n - 1.0);
    double sd = sqrt(var);
    stats[0] = mean; stats[1] = sd;
    stats[2] = 0.8 / mean;
    stats[3] = 0.8 / sd;
  }
}

// ---- weight norm, transposed output wt[k][i][o] = g[o]/||v[o]|| * v[o,i,k] ----
__global__ __launch_bounds__(256) void weight_norm(const float* __restrict__ v,
                                                   const float* __restrict__ g,
                                                   float* __restrict__ wt) {
  int o = blockIdx.x;
  __shared__ float red[256];
  __shared__ float scale;
  int tid = threadIdx.x;
  float vv = (tid < 192) ? v[o * 192 + tid] : 0.f;
  red[tid] = vv * vv;
  __syncthreads();
  for (int s = 128; s > 0; s >>= 1) {
    if (tid < s) red[tid] += red[tid + s];
    __syncthreads();
  }
  if (tid == 0) scale = g[o] / sqrtf(red[0]);
  __syncthreads();
  if (tid < 192) {
    int i = tid / 3, k = tid - 3 * i;
    wt[(k * 64 + i) * 64 + o] = scale * vv;
  }
}

// ---------------- closed-form index helpers ----------------
__device__ __host__ inline int pad_idx(int p, int brk, int dup, int sub) {
  if (p < brk) { int q = p / 3; int r = p - 3 * q; return 2 * q + (r == 2 ? 1 : 0); }
  if (p < brk + 2) return dup;
  return p - sub;
}

__device__ inline int fmap_code(int k) {
  if (k == 0) return 2048 + 0;
  if (k == 1) return 0;
  if (k < 5462) {
    int m = k - 2;
    int c = m / 12;
    int j = m - 12 * c;
    if (j <= 3)  return 2048 + (1 + 9 * c + j);
    if (j == 4)  return 1 + 3 * c;
    if (j <= 8)  return 2048 + (9 * c + j);
    if (j == 9)  return 2 + 3 * c;
    if (j == 10) return 2048 + (9 + 9 * c);
    return 3 + 3 * c;
  }
  return k - 4096;
}

// ---- fused conv (stride2, dil3) + bias + maxpool(3,s2,p1) + elu + gauss ----
// lane = conv-output u, wave = 16-channel slice of o. J phases staged in LDS,
// weights wave-uniform (s_load). cbf aliased onto Jbuf (saves LDS -> 4 blk/CU).
#define JROWS 46
#define JSTR  68
__global__ __launch_bounds__(256) void conv_pool(
    const float* __restrict__ x, const float* __restrict__ wt,
    const float* __restrict__ cbias, const double* __restrict__ stats,
    float* __restrict__ y1, int L, int U, int V, int mult, int off1) {
  const int b = blockIdx.x;
  const int v0 = blockIdx.y * 31;
  const int tid = threadIdx.x;
  const int lane = tid & 63;
  const int wave = tid >> 6;
  const int og = wave * 16;

  const int u0 = 2 * v0 - 1;
  const int uv_lo = max(u0, 0);
  const int uv_hi = min(u0 + 63, U - 1);
  const int t_lo = (2 * uv_lo) / 3;
  int t_hi = (2 * uv_hi + 6) / 3;
  if (t_hi > L - 1) t_hi = L - 1;
  const int rows = t_hi - t_lo + 1;      // <= 46

  __shared__ float smem[3 * JROWS * JSTR];   // J phases; later aliased as cbf[64][64]
  float* Jb = smem;
  float* cbf = smem;                          // 64*64 floats = 16 KB < 37.5 KB

  const float inv_mean = (float)stats[2];
  const float inv_std  = (float)stats[3];
  const long xbase = (long)b * TT * CC;

  for (int idx = tid; idx < rows * 64; idx += 256) {
    int tr = idx >> 6, c = idx & 63;
    int t = t_lo + tr;
    float x0 = x[xbase + (long)(mult * t) * CC + c];
    float x1 = x[xbase + (long)(mult * t + off1) * CC + c];
    Jb[(0 * JROWS + tr) * JSTR + c] = fmaf(inv_mean, x1, 0.2f * x0);
    Jb[(1 * JROWS + tr) * JSTR + c] = x0;
    Jb[(2 * JROWS + tr) * JSTR + c] = fmaf(inv_std,  x1, 0.2f * x0);
  }
  __syncthreads();

  const int u = u0 + lane;
  const bool valid = (u >= 0) && (u < U);
  const int uc = min(max(u, 0), U - 1);
  const int t0 = (2 * uc) / 3;
  const int r = 2 * uc - 3 * t0;
  const int tr = t0 - t_lo;
  const float* Jrow = Jb + (r * JROWS + tr) * JSTR;

  float acc[16];
#pragma unroll
  for (int o = 0; o < 16; o++) acc[o] = cbias[og + o];

#pragma unroll
  for (int k = 0; k < 3; k++) {
    const float4* row = (const float4*)(Jrow + k * JSTR);
    const float* wk = wt + (k * 64) * 64 + og;
#pragma unroll 4
    for (int i4 = 0; i4 < 16; i4++) {
      float4 jv = row[i4];
      const float* wp = wk + i4 * 4 * 64;
#pragma unroll
      for (int o = 0; o < 16; o++) {
        float a0 = fmaf(jv.x, wp[o],       acc[o]);
        float a1 = fmaf(jv.y, wp[64 + o],  a0);
        float a2 = fmaf(jv.z, wp[128 + o], a1);
        acc[o]   = fmaf(jv.w, wp[192 + o], a2);
      }
    }
  }

  __syncthreads();   // Jbuf dead from here; reuse as cbf
#pragma unroll
  for (int o = 0; o < 16; o++)
    cbf[(og + o) * 64 + lane] = valid ? acc[o] : -INFINITY;
  __syncthreads();

  const int vl = lane;
  if (vl < 31) {
    int v = v0 + vl;
    if (v < V) {
#pragma unroll
      for (int o = 0; o < 16; o++) {
        const float* cr = cbf + (og + o) * 64 + 2 * vl;
        float m = fmaxf(fmaxf(cr[0], cr[1]), cr[2]);
        float e = (m > 0.f) ? m : (expf(m) - 1.f);
        y1[((long)(b * 64 + og + o)) * V + v] = expf(-0.5f * e * e);
      }
    }
  }
}

// ---------------- batchnorm statistics: partial (grid c x 8) + final ----------------
__global__ __launch_bounds__(256) void bn_partial(const float* __restrict__ y1,
                                                  double* __restrict__ part,
                                                  int V, int P, int brk, int dup, int sub) {
  const int c = blockIdx.x, chunk = blockIdx.y;
  const int len = BB * P / 8;
  const int start = chunk * len;
  __shared__ double s1[256], s2[256];
  double a = 0, q = 0;
  for (int idx = start + threadIdx.x; idx < start + len; idx += 256) {
    int b = idx / P, p = idx - b * P;
    float v = y1[((long)(b * 64 + c)) * V + pad_idx(p, brk, dup, sub)];
    a += v; q += (double)v * (double)v;
  }
  s1[threadIdx.x] = a; s2[threadIdx.x] = q;
  __syncthreads();
  for (int s = 128; s > 0; s >>= 1) {
    if (threadIdx.x < s) { s1[threadIdx.x] += s1[threadIdx.x + s]; s2[threadIdx.x] += s2[threadIdx.x + s]; }
    __syncthreads();
  }
  if (threadIdx.x == 0) {
    part[(c * 8 + chunk) * 2]     = s1[0];
    part[(c * 8 + chunk) * 2 + 1] = s2[0];
  }
}

__global__ __launch_bounds__(128) void bn_final(const double* __restrict__ p0,
                                                const double* __restrict__ p1,
                                                float* __restrict__ bnp0,
                                                float* __restrict__ bnp1) {
  int t = threadIdx.x;
  const double* pp = (t < 64) ? p0 : p1;
  int c = t & 63;
  double n = (t < 64) ? (double)BB * P0v : (double)BB * P1v;
  double a = 0, q = 0;
  for (int j = 0; j < 8; j++) { a += pp[(c * 8 + j) * 2]; q += pp[(c * 8 + j) * 2 + 1]; }
  double mu = a / n;
  double var = q / n - mu * mu;
  float* bp = (t < 64) ? bnp0 : bnp1;
  bp[2 * c] = (float)mu;
  bp[2 * c + 1] = 1.0f / sqrtf((float)var + 1e-5f);
}

// ---------------- fused finalize + sew-up gather ----------------
__global__ __launch_bounds__(256) void final_fused(
    const float* __restrict__ x, const float* __restrict__ y10,
    const float* __restrict__ y11, const float* __restrict__ bnp0,
    const float* __restrict__ bnp1, const float* __restrict__ gamma,
    const float* __restrict__ beta, float* __restrict__ out) {
  long idx = (long)blockIdx.x * 256 + threadIdx.x;
  if (idx >= (long)BB * CC * OUTL) return;
  int k = (int)(idx % OUTL);
  long bc = idx / OUTL;
  int c = (int)(bc & 63);
  long b = bc >> 6;
  const long xb = b * TT * CC;
  int s = fmap_code(k);
  float v;
  if (s < 2048) {
    if ((s & 1) == 0) {
      v = x[xb + (long)(2 * s) * CC + c];
    } else {
      int p = s >> 1;
      int pi = pad_idx(p, 768, 512, 257);
      float yv = y11[bc * V1v + pi];
      float z = gamma[c] * (yv - bnp1[2 * c]) * bnp1[2 * c + 1] + beta[c];
      float e = (z > 0.f) ? z : (expf(z) - 1.f);
      v = x[xb + (long)(4 * p + 3) * CC + c] + e;
    }
  } else {
    int p = s - 2048;
    if ((p & 1) == 0) {
      v = x[xb + (long)p * CC + c];
    } else {
      int q = p >> 1;
      int pi = pad_idx(q, 1536, 1024, 513);
      float yv = y10[bc * V0v + pi];
      float z = gamma[c] * (yv - bnp0[2 * c]) * bnp0[2 * c + 1] + beta[c];
      float e = (z > 0.f) ? z : (expf(z) - 1.f);
      v = x[xb + (long)(2 * q + 1) * CC + c] + e;
    }
  }
  out[idx] = v;
}

extern "C" void kernel_launch(void* const* d_in, const int* in_sizes, int n_in,
                              void* d_out, int out_size, void* d_ws, size_t ws_size,
                              hipStream_t stream) {
  const float* x   = (const float*)d_in[0];
  const float* cv  = (const float*)d_in[1];
  const float* cg  = (const float*)d_in[2];
  const float* cb  = (const float*)d_in[3];
  const float* gam = (const float*)d_in[4];
  const float* bet = (const float*)d_in[5];
  float* out = (float*)d_out;

  char* ws = (char*)d_ws;
  size_t cur = 0;
  auto alloc = [&](size_t bytes) -> char* {
    char* p = ws + cur;
    cur = (cur + bytes + 255) & ~(size_t)255;
    return p;
  };
  double* part   = (double*)alloc(1024 * 2 * sizeof(double));
  double* stats  = (double*)alloc(4 * sizeof(double));
  float*  wt     = (float*)alloc(3 * 64 * 64 * sizeof(float));
  double* bnpt0  = (double*)alloc(64 * 8 * 2 * sizeof(double));
  double* bnpt1  = (double*)alloc(64 * 8 * 2 * sizeof(double));
  float*  bnp0   = (float*)alloc(128 * sizeof(float));
  float*  bnp1   = (float*)alloc(128 * sizeof(float));
  float*  y10    = (float*)alloc((size_t)4096 * V0v * sizeof(float));
  float*  y11    = (float*)alloc((size_t)4096 * V1v * sizeof(float));

  stats_partial<<<1024, 256, 0, stream>>>(x, part);
  stats_final<<<1, 256, 0, stream>>>(part, stats);
  weight_norm<<<64, 256, 0, stream>>>(cv, cg, wt);

  conv_pool<<<dim3(64, (V0v + 30) / 31), 256, 0, stream>>>(x, wt, cb, stats, y10, L0v, U0v, V0v, 2, 1);
  conv_pool<<<dim3(64, (V1v + 30) / 31), 256, 0, stream>>>(x, wt, cb, stats, y11, L1v, U1v, V1v, 4, 3);

  bn_partial<<<dim3(64, 8), 256, 0, stream>>>(y10, bnpt0, V0v, P0v, 1536, 1024, 513);
  bn_partial<<<dim3(64, 8), 256, 0, stream>>>(y11, bnpt1, V1v, P1v, 768, 512, 257);
  bn_final<<<1, 128, 0, stream>>>(bnpt0, bnpt1, bnp0, bnp1);

  long ntot_out = (long)BB * CC * OUTL;
  final_fused<<<(int)((ntot_out + 255) / 256), 256, 0, stream>>>(x, y10, y11, bnp0, bnp1, gam, bet, out);
}

// Round 3
// 457.157 us; speedup vs baseline: 3.2127x; 1.7103x over previous
//
#include <hip/hip_runtime.h>
#include <math.h>

#define BB 64
#define TT 4096
#define CC 64

constexpr int L0v = 2048, U0v = 3069, V0v = 1535, P0v = 2048;
constexpr int L1v = 1024, U1v = 1533, V1v = 767,  P1v = 1024;
constexpr int OUTL = 6144;
constexpr long NTOT = (long)BB * TT * CC;

// ---- transpose x[b][t][c] -> xtr[b][c][t], fused global sum/sumsq ----
__global__ __launch_bounds__(256) void transpose_stats(const float* __restrict__ x,
                                                       float* __restrict__ xtr,
                                                       double* __restrict__ part) {
  __shared__ float tile[64][65];
  __shared__ double sd1[256], sd2[256];
  const int tt = blockIdx.x;
  const int b = blockIdx.y;
  const int t0 = tt * 64;
  const long xbase = (long)b * TT * CC + (long)t0 * CC;
  const int tid = threadIdx.x;
  double a = 0, q = 0;
  {
    int c = tid & 63;
    for (int r = tid >> 6; r < 64; r += 4) {
      float v = x[xbase + r * 64 + c];
      tile[r][c] = v;
      a += v; q += (double)v * (double)v;
    }
  }
  sd1[tid] = a; sd2[tid] = q;
  __syncthreads();
  {
    int tl = tid & 63;
    for (int cc = tid >> 6; cc < 64; cc += 4)
      xtr[((long)(b * 64 + cc)) * TT + t0 + tl] = tile[tl][cc];
  }
  for (int s = 128; s > 0; s >>= 1) {
    if (tid < s) { sd1[tid] += sd1[tid + s]; sd2[tid] += sd2[tid + s]; }
    __syncthreads();
  }
  if (tid == 0) {
    part[(b * 64 + tt) * 2] = sd1[0];
    part[(b * 64 + tt) * 2 + 1] = sd2[0];
  }
}

__global__ __launch_bounds__(256) void stats_final(const double* __restrict__ part,
                                                   double* __restrict__ stats) {
  __shared__ double s1[256], s2[256];
  double a = 0, q = 0;
  for (int i = threadIdx.x; i < 4096; i += 256) { a += part[2 * i]; q += part[2 * i + 1]; }
  s1[threadIdx.x] = a; s2[threadIdx.x] = q;
  __syncthreads();
  for (int s = 128; s > 0; s >>= 1) {
    if (threadIdx.x < s) { s1[threadIdx.x] += s1[threadIdx.x + s]; s2[threadIdx.x] += s2[threadIdx.x + s]; }
    __syncthreads();
  }
  if (threadIdx.x == 0) {
    double n = (double)NTOT;
    double mean = s1[0] / n;
    double var = (s2[0] - s1[0] * s1[0] / n) / (n - 1.0);
    double sd = sqrt(var);
    stats[0] = mean; stats[1] = sd;
    stats[2] = 0.8 / mean;
    stats[3] = 0.8 / sd;
  }
}

// ---- weight norm, transposed output wt[k][i][o] = g[o]/||v[o]|| * v[o,i,k] ----
__global__ __launch_bounds__(256) void weight_norm(const float* __restrict__ v,
                                                   const float* __restrict__ g,
                                                   float* __restrict__ wt) {
  int o = blockIdx.x;
  __shared__ float red[256];
  __shared__ float scale;
  int tid = threadIdx.x;
  float vv = (tid < 192) ? v[o * 192 + tid] : 0.f;
  red[tid] = vv * vv;
  __syncthreads();
  for (int s = 128; s > 0; s >>= 1) {
    if (tid < s) red[tid] += red[tid + s];
    __syncthreads();
  }
  if (tid == 0) scale = g[o] / sqrtf(red[0]);
  __syncthreads();
  if (tid < 192) {
    int i = tid / 3, k = tid - 3 * i;
    wt[(k * 64 + i) * 64 + o] = scale * vv;
  }
}

// ---------------- closed-form index helpers ----------------
__device__ __host__ inline int pad_idx(int p, int brk, int dup, int sub) {
  if (p < brk) { int q = p / 3; int r = p - 3 * q; return 2 * q + (r == 2 ? 1 : 0); }
  if (p < brk + 2) return dup;
  return p - sub;
}

__device__ inline int fmap_code(int k) {
  if (k == 0) return 2048 + 0;
  if (k == 1) return 0;
  if (k < 5462) {
    int m = k - 2;
    int c = m / 12;
    int j = m - 12 * c;
    if (j <= 3)  return 2048 + (1 + 9 * c + j);
    if (j == 4)  return 1 + 3 * c;
    if (j <= 8)  return 2048 + (9 * c + j);
    if (j == 9)  return 2 + 3 * c;
    if (j == 10) return 2048 + (9 + 9 * c);
    return 3 + 3 * c;
  }
  return k - 4096;
}

// ---- fused conv (stride2, dil3) + bias + maxpool(3,s2,p1) + elu + gauss ----
// lane = conv-output u; wave = 16-channel slice of o. J phases in LDS (ds_read_b128),
// weights via SGPR (readfirstlane base -> s_load), pure v_fma inner loop.
#define JROWS 46
#define JSTR  68
__global__ __launch_bounds__(256) void conv_pool(
    const float* __restrict__ x, const float* __restrict__ wt,
    const float* __restrict__ cbias, const double* __restrict__ stats,
    float* __restrict__ y1, int L, int U, int V, int mult, int off1) {
  const int b = blockIdx.x;
  const int v0 = blockIdx.y * 31;
  const int tid = threadIdx.x;
  const int lane = tid & 63;
  const int wave = tid >> 6;
  const int og_s = __builtin_amdgcn_readfirstlane(wave * 16);

  const int u0 = 2 * v0 - 1;
  const int uv_lo = max(u0, 0);
  const int uv_hi = min(u0 + 63, U - 1);
  const int t_lo = (2 * uv_lo) / 3;
  int t_hi = (2 * uv_hi + 6) / 3;
  if (t_hi > L - 1) t_hi = L - 1;
  const int rows = t_hi - t_lo + 1;      // <= 46

  __shared__ float smem[3 * JROWS * JSTR];   // J phases; later aliased as cbf[64][64]
  float* Jb = smem;
  float* cbf = smem;

  const float inv_mean = (float)stats[2];
  const float inv_std  = (float)stats[3];
  const long xbase = (long)b * TT * CC;

  for (int idx = tid; idx < rows * 64; idx += 256) {
    int tr = idx >> 6, c = idx & 63;
    int t = t_lo + tr;
    float x0 = x[xbase + (long)(mult * t) * CC + c];
    float x1 = x[xbase + (long)(mult * t + off1) * CC + c];
    Jb[(0 * JROWS + tr) * JSTR + c] = fmaf(inv_mean, x1, 0.2f * x0);
    Jb[(1 * JROWS + tr) * JSTR + c] = x0;
    Jb[(2 * JROWS + tr) * JSTR + c] = fmaf(inv_std,  x1, 0.2f * x0);
  }
  __syncthreads();

  const int u = u0 + lane;
  const bool valid = (u >= 0) && (u < U);
  const int uc = min(max(u, 0), U - 1);
  const int t0 = (2 * uc) / 3;
  const int r = 2 * uc - 3 * t0;
  const int tr = t0 - t_lo;
  const float* Jrow = Jb + (r * JROWS + tr) * JSTR;

  float acc[16];
  {
    const float* cb_s = cbias + og_s;
#pragma unroll
    for (int o = 0; o < 16; o++) acc[o] = cb_s[o];
  }

#pragma unroll
  for (int k = 0; k < 3; k++) {
    const float4* row = (const float4*)(Jrow + k * JSTR);
    const float* wk = wt + (k * 64) * 64 + og_s;
#pragma unroll 4
    for (int i4 = 0; i4 < 16; i4++) {
      float4 jv = row[i4];
      const float* wp = wk + i4 * 256;
#pragma unroll
      for (int o = 0; o < 16; o++) {
        float a0 = fmaf(jv.x, wp[o],       acc[o]);
        float a1 = fmaf(jv.y, wp[64 + o],  a0);
        float a2 = fmaf(jv.z, wp[128 + o], a1);
        acc[o]   = fmaf(jv.w, wp[192 + o], a2);
      }
    }
  }

  __syncthreads();   // Jbuf dead; reuse as cbf[64][64]
#pragma unroll
  for (int o = 0; o < 16; o++)
    cbf[(og_s + o) * 64 + lane] = valid ? acc[o] : -INFINITY;
  __syncthreads();

  if (lane < 31) {
    int v = v0 + lane;
    if (v < V) {
#pragma unroll
      for (int o = 0; o < 16; o++) {
        const float* cr = cbf + (og_s + o) * 64 + 2 * lane;
        float m = fmaxf(fmaxf(cr[0], cr[1]), cr[2]);
        float e = (m > 0.f) ? m : (expf(m) - 1.f);
        y1[((long)(b * 64 + og_s + o)) * V + v] = expf(-0.5f * e * e);
      }
    }
  }
}

// ---------------- batchnorm statistics: partial (grid c x 8) + final ----------------
__global__ __launch_bounds__(256) void bn_partial(const float* __restrict__ y1,
                                                  double* __restrict__ part,
                                                  int V, int P, int brk, int dup, int sub) {
  const int c = blockIdx.x, chunk = blockIdx.y;
  const int len = BB * P / 8;
  const int start = chunk * len;
  __shared__ double s1[256], s2[256];
  double a = 0, q = 0;
  for (int idx = start + threadIdx.x; idx < start + len; idx += 256) {
    int b = idx / P, p = idx - b * P;
    float v = y1[((long)(b * 64 + c)) * V + pad_idx(p, brk, dup, sub)];
    a += v; q += (double)v * (double)v;
  }
  s1[threadIdx.x] = a; s2[threadIdx.x] = q;
  __syncthreads();
  for (int s = 128; s > 0; s >>= 1) {
    if (threadIdx.x < s) { s1[threadIdx.x] += s1[threadIdx.x + s]; s2[threadIdx.x] += s2[threadIdx.x + s]; }
    __syncthreads();
  }
  if (threadIdx.x == 0) {
    part[(c * 8 + chunk) * 2]     = s1[0];
    part[(c * 8 + chunk) * 2 + 1] = s2[0];
  }
}

__global__ __launch_bounds__(128) void bn_final(const double* __restrict__ p0,
                                                const double* __restrict__ p1,
                                                float* __restrict__ bnp0,
                                                float* __restrict__ bnp1) {
  int t = threadIdx.x;
  const double* pp = (t < 64) ? p0 : p1;
  int c = t & 63;
  double n = (t < 64) ? (double)BB * P0v : (double)BB * P1v;
  double a = 0, q = 0;
  for (int j = 0; j < 8; j++) { a += pp[(c * 8 + j) * 2]; q += pp[(c * 8 + j) * 2 + 1]; }
  double mu = a / n;
  double var = q / n - mu * mu;
  float* bp = (t < 64) ? bnp0 : bnp1;
  bp[2 * c] = (float)mu;
  bp[2 * c + 1] = 1.0f / sqrtf((float)var + 1e-5f);
}

// ---------------- fused finalize + sew-up gather (reads xtr, coalesced-ish) ----------
__global__ __launch_bounds__(256) void final_fused(
    const float* __restrict__ xtr, const float* __restrict__ y10,
    const float* __restrict__ y11, const float* __restrict__ bnp0,
    const float* __restrict__ bnp1, const float* __restrict__ gamma,
    const float* __restrict__ beta, float* __restrict__ out) {
  long idx = (long)blockIdx.x * 256 + threadIdx.x;
  if (idx >= (long)BB * CC * OUTL) return;
  int k = (int)(idx % OUTL);
  long bc = idx / OUTL;
  int c = (int)(bc & 63);
  const float* xr = xtr + bc * TT;
  int s = fmap_code(k);
  float v;
  if (s < 2048) {
    if ((s & 1) == 0) {
      v = xr[2 * s];
    } else {
      int p = s >> 1;
      int pi = pad_idx(p, 768, 512, 257);
      float yv = y11[bc * V1v + pi];
      float z = gamma[c] * (yv - bnp1[2 * c]) * bnp1[2 * c + 1] + beta[c];
      float e = (z > 0.f) ? z : (expf(z) - 1.f);
      v = xr[4 * p + 3] + e;
    }
  } else {
    int p = s - 2048;
    if ((p & 1) == 0) {
      v = xr[p];
    } else {
      int q = p >> 1;
      int pi = pad_idx(q, 1536, 1024, 513);
      float yv = y10[bc * V0v + pi];
      float z = gamma[c] * (yv - bnp0[2 * c]) * bnp0[2 * c + 1] + beta[c];
      float e = (z > 0.f) ? z : (expf(z) - 1.f);
      v = xr[2 * q + 1] + e;
    }
  }
  out[idx] = v;
}

extern "C" void kernel_launch(void* const* d_in, const int* in_sizes, int n_in,
                              void* d_out, int out_size, void* d_ws, size_t ws_size,
                              hipStream_t stream) {
  const float* x   = (const float*)d_in[0];
  const float* cv  = (const float*)d_in[1];
  const float* cg  = (const float*)d_in[2];
  const float* cb  = (const float*)d_in[3];
  const float* gam = (const float*)d_in[4];
  const float* bet = (const float*)d_in[5];
  float* out = (float*)d_out;

  char* ws = (char*)d_ws;
  size_t cur = 0;
  auto alloc = [&](size_t bytes) -> char* {
    char* p = ws + cur;
    cur = (cur + bytes + 255) & ~(size_t)255;
    return p;
  };
  double* part   = (double*)alloc(4096 * 2 * sizeof(double));
  double* stats  = (double*)alloc(4 * sizeof(double));
  float*  wt     = (float*)alloc(3 * 64 * 64 * sizeof(float));
  double* bnpt0  = (double*)alloc(64 * 8 * 2 * sizeof(double));
  double* bnpt1  = (double*)alloc(64 * 8 * 2 * sizeof(double));
  float*  bnp0   = (float*)alloc(128 * sizeof(float));
  float*  bnp1   = (float*)alloc(128 * sizeof(float));
  float*  xtr    = (float*)alloc((size_t)BB * CC * TT * sizeof(float));
  float*  y10    = (float*)alloc((size_t)4096 * V0v * sizeof(float));
  float*  y11    = (float*)alloc((size_t)4096 * V1v * sizeof(float));

  transpose_stats<<<dim3(64, 64), 256, 0, stream>>>(x, xtr, part);
  stats_final<<<1, 256, 0, stream>>>(part, stats);
  weight_norm<<<64, 256, 0, stream>>>(cv, cg, wt);

  conv_pool<<<dim3(64, (V0v + 30) / 31), 256, 0, stream>>>(x, wt, cb, stats, y10, L0v, U0v, V0v, 2, 1);
  conv_pool<<<dim3(64, (V1v + 30) / 31), 256, 0, stream>>>(x, wt, cb, stats, y11, L1v, U1v, V1v, 4, 3);

  bn_partial<<<dim3(64, 8), 256, 0, stream>>>(y10, bnpt0, V0v, P0v, 1536, 1024, 513);
  bn_partial<<<dim3(64, 8), 256, 0, stream>>>(y11, bnpt1, V1v, P1v, 768, 512, 257);
  bn_final<<<1, 128, 0, stream>>>(bnpt0, bnpt1, bnp0, bnp1);

  long ntot_out = (long)BB * CC * OUTL;
  final_fused<<<(int)((ntot_out + 255) / 256), 256, 0, stream>>>(xtr, y10, y11, bnp0, bnp1, gam, bet, out);
}

// Round 4
// 402.880 us; speedup vs baseline: 3.6455x; 1.1347x over previous
//
#include <hip/hip_runtime.h>
#include <math.h>

#define BB 64
#define TT 4096
#define CC 64

constexpr int L0v = 2048, U0v = 3069, V0v = 1535, P0v = 2048;
constexpr int L1v = 1024, U1v = 1533, V1v = 767,  P1v = 1024;
constexpr int OUTL = 6144;
constexpr long NTOT = (long)BB * TT * CC;

// ---- transpose x[b][t][c] -> xtr[b][c][t], fused global sum/sumsq ----
__global__ __launch_bounds__(256) void transpose_stats(const float* __restrict__ x,
                                                       float* __restrict__ xtr,
                                                       double* __restrict__ part) {
  __shared__ float tile[64][65];
  __shared__ double sd1[256], sd2[256];
  const int tt = blockIdx.x;
  const int b = blockIdx.y;
  const int t0 = tt * 64;
  const long xbase = (long)b * TT * CC + (long)t0 * CC;
  const int tid = threadIdx.x;
  double a = 0, q = 0;
  {
    int c = tid & 63;
    for (int r = tid >> 6; r < 64; r += 4) {
      float v = x[xbase + r * 64 + c];
      tile[r][c] = v;
      a += v; q += (double)v * (double)v;
    }
  }
  sd1[tid] = a; sd2[tid] = q;
  __syncthreads();
  {
    int tl = tid & 63;
    for (int cc = tid >> 6; cc < 64; cc += 4)
      xtr[((long)(b * 64 + cc)) * TT + t0 + tl] = tile[tl][cc];
  }
  for (int s = 128; s > 0; s >>= 1) {
    if (tid < s) { sd1[tid] += sd1[tid + s]; sd2[tid] += sd2[tid + s]; }
    __syncthreads();
  }
  if (tid == 0) {
    part[(b * 64 + tt) * 2] = sd1[0];
    part[(b * 64 + tt) * 2 + 1] = sd2[0];
  }
}

__global__ __launch_bounds__(256) void stats_final(const double* __restrict__ part,
                                                   double* __restrict__ stats) {
  __shared__ double s1[256], s2[256];
  double a = 0, q = 0;
  for (int i = threadIdx.x; i < 4096; i += 256) { a += part[2 * i]; q += part[2 * i + 1]; }
  s1[threadIdx.x] = a; s2[threadIdx.x] = q;
  __syncthreads();
  for (int s = 128; s > 0; s >>= 1) {
    if (threadIdx.x < s) { s1[threadIdx.x] += s1[threadIdx.x + s]; s2[threadIdx.x] += s2[threadIdx.x + s]; }
    __syncthreads();
  }
  if (threadIdx.x == 0) {
    double n = (double)NTOT;
    double mean = s1[0] / n;
    double var = (s2[0] - s1[0] * s1[0] / n) / (n - 1.0);
    double sd = sqrt(var);
    stats[0] = mean; stats[1] = sd;
    stats[2] = 0.8 / mean;
    stats[3] = 0.8 / sd;
  }
}

// ---- weight norm, transposed output wt[k][i][o] = g[o]/||v[o]|| * v[o,i,k] ----
__global__ __launch_bounds__(256) void weight_norm(const float* __restrict__ v,
                                                   const float* __restrict__ g,
                                                   float* __restrict__ wt) {
  int o = blockIdx.x;
  __shared__ float red[256];
  __shared__ float scale;
  int tid = threadIdx.x;
  float vv = (tid < 192) ? v[o * 192 + tid] : 0.f;
  red[tid] = vv * vv;
  __syncthreads();
  for (int s = 128; s > 0; s >>= 1) {
    if (tid < s) red[tid] += red[tid + s];
    __syncthreads();
  }
  if (tid == 0) scale = g[o] / sqrtf(red[0]);
  __syncthreads();
  if (tid < 192) {
    int i = tid / 3, k = tid - 3 * i;
    wt[(k * 64 + i) * 64 + o] = scale * vv;
  }
}

// ---------------- closed-form index helpers ----------------
__device__ __host__ inline int pad_idx(int p, int brk, int dup, int sub) {
  if (p < brk) { int q = p / 3; int r = p - 3 * q; return 2 * q + (r == 2 ? 1 : 0); }
  if (p < brk + 2) return dup;
  return p - sub;
}

__device__ inline int fmap_code(int k) {
  if (k == 0) return 2048 + 0;
  if (k == 1) return 0;
  if (k < 5462) {
    int m = k - 2;
    int c = m / 12;
    int j = m - 12 * c;
    if (j <= 3)  return 2048 + (1 + 9 * c + j);
    if (j == 4)  return 1 + 3 * c;
    if (j <= 8)  return 2048 + (9 * c + j);
    if (j == 9)  return 2 + 3 * c;
    if (j == 10) return 2048 + (9 + 9 * c);
    return 3 + 3 * c;
  }
  return k - 4096;
}

// ---- precompute packed gather codes: [yi:11 | xi:12 | type:2] ----
__global__ __launch_bounds__(256) void build_codes(int* __restrict__ codes) {
  int k = blockIdx.x * 256 + threadIdx.x;
  if (k >= OUTL) return;
  int s = fmap_code(k);
  int type, xi, yi = 0;
  if (s < 2048) {
    if ((s & 1) == 0) { type = 0; xi = 2 * s; }
    else { int p = s >> 1; yi = pad_idx(p, 768, 512, 257); xi = 4 * p + 3; type = 2; }
  } else {
    int p = s - 2048;
    if ((p & 1) == 0) { type = 0; xi = p; }
    else { int q = p >> 1; yi = pad_idx(q, 1536, 1024, 513); xi = 2 * q + 1; type = 1; }
  }
  codes[k] = type | (xi << 2) | (yi << 14);
}

// ---- fused conv (stride2, dil3) + bias + maxpool(3,s2,p1) + elu + gauss ----
#define JROWS 46
#define JSTR  68
__global__ __launch_bounds__(256) void conv_pool(
    const float* __restrict__ x, const float* __restrict__ wt,
    const float* __restrict__ cbias, const double* __restrict__ stats,
    float* __restrict__ y1, int L, int U, int V, int mult, int off1) {
  const int b = blockIdx.x;
  const int v0 = blockIdx.y * 31;
  const int tid = threadIdx.x;
  const int lane = tid & 63;
  const int wave = tid >> 6;
  const int og_s = __builtin_amdgcn_readfirstlane(wave * 16);

  const int u0 = 2 * v0 - 1;
  const int uv_lo = max(u0, 0);
  const int uv_hi = min(u0 + 63, U - 1);
  const int t_lo = (2 * uv_lo) / 3;
  int t_hi = (2 * uv_hi + 6) / 3;
  if (t_hi > L - 1) t_hi = L - 1;
  const int rows = t_hi - t_lo + 1;      // <= 46

  __shared__ float smem[3 * JROWS * JSTR];
  float* Jb = smem;
  float* cbf = smem;

  const float inv_mean = (float)stats[2];
  const float inv_std  = (float)stats[3];
  const long xbase = (long)b * TT * CC;

  for (int idx = tid; idx < rows * 64; idx += 256) {
    int tr = idx >> 6, c = idx & 63;
    int t = t_lo + tr;
    float x0 = x[xbase + (long)(mult * t) * CC + c];
    float x1 = x[xbase + (long)(mult * t + off1) * CC + c];
    Jb[(0 * JROWS + tr) * JSTR + c] = fmaf(inv_mean, x1, 0.2f * x0);
    Jb[(1 * JROWS + tr) * JSTR + c] = x0;
    Jb[(2 * JROWS + tr) * JSTR + c] = fmaf(inv_std,  x1, 0.2f * x0);
  }
  __syncthreads();

  const int u = u0 + lane;
  const bool valid = (u >= 0) && (u < U);
  const int uc = min(max(u, 0), U - 1);
  const int t0 = (2 * uc) / 3;
  const int r = 2 * uc - 3 * t0;
  const int tr = t0 - t_lo;
  const float* Jrow = Jb + (r * JROWS + tr) * JSTR;

  float acc[16];
  {
    const float* cb_s = cbias + og_s;
#pragma unroll
    for (int o = 0; o < 16; o++) acc[o] = cb_s[o];
  }

#pragma unroll
  for (int k = 0; k < 3; k++) {
    const float4* row = (const float4*)(Jrow + k * JSTR);
    const float* wk = wt + (k * 64) * 64 + og_s;
#pragma unroll 4
    for (int i4 = 0; i4 < 16; i4++) {
      float4 jv = row[i4];
      const float* wp = wk + i4 * 256;
#pragma unroll
      for (int o = 0; o < 16; o++) {
        float a0 = fmaf(jv.x, wp[o],       acc[o]);
        float a1 = fmaf(jv.y, wp[64 + o],  a0);
        float a2 = fmaf(jv.z, wp[128 + o], a1);
        acc[o]   = fmaf(jv.w, wp[192 + o], a2);
      }
    }
  }

  __syncthreads();
#pragma unroll
  for (int o = 0; o < 16; o++)
    cbf[(og_s + o) * 64 + lane] = valid ? acc[o] : -INFINITY;
  __syncthreads();

  if (lane < 31) {
    int v = v0 + lane;
    if (v < V) {
#pragma unroll
      for (int o = 0; o < 16; o++) {
        const float* cr = cbf + (og_s + o) * 64 + 2 * lane;
        float m = fmaxf(fmaxf(cr[0], cr[1]), cr[2]);
        float e = (m > 0.f) ? m : (expf(m) - 1.f);
        y1[((long)(b * 64 + og_s + o)) * V + v] = expf(-0.5f * e * e);
      }
    }
  }
}

// ---- batchnorm stats: weighted sequential sum (equiv to dpad gather) ----
// weight(v) = 2-(v&1) for v<mid ; 2 at v==mid ; 1 for v>mid
__global__ __launch_bounds__(256) void bn_partial(const float* __restrict__ y1,
                                                  double* __restrict__ part,
                                                  int V, int mid) {
  const int c = blockIdx.x, chunk = blockIdx.y;   // chunk: 8 b's each
  __shared__ double s1[256], s2[256];
  double a = 0, q = 0;
  for (int b = chunk * 8; b < chunk * 8 + 8; b++) {
    const float* row = y1 + ((long)(b * 64 + c)) * V;
    for (int v = threadIdx.x; v < V; v += 256) {
      float val = row[v];
      float w = (v < mid) ? (float)(2 - (v & 1)) : ((v == mid) ? 2.f : 1.f);
      float wv = w * val;
      a += wv; q += (double)wv * (double)val;
    }
  }
  s1[threadIdx.x] = a; s2[threadIdx.x] = q;
  __syncthreads();
  for (int s = 128; s > 0; s >>= 1) {
    if (threadIdx.x < s) { s1[threadIdx.x] += s1[threadIdx.x + s]; s2[threadIdx.x] += s2[threadIdx.x + s]; }
    __syncthreads();
  }
  if (threadIdx.x == 0) {
    part[(c * 8 + chunk) * 2]     = s1[0];
    part[(c * 8 + chunk) * 2 + 1] = s2[0];
  }
}

// ---- bn final -> affine coefficients: z = A*y + B ----
__global__ __launch_bounds__(128) void bn_final(const double* __restrict__ p0,
                                                const double* __restrict__ p1,
                                                const float* __restrict__ gamma,
                                                const float* __restrict__ beta,
                                                float* __restrict__ cf0,
                                                float* __restrict__ cf1) {
  int t = threadIdx.x;
  const double* pp = (t < 64) ? p0 : p1;
  int c = t & 63;
  double n = (t < 64) ? (double)BB * P0v : (double)BB * P1v;
  double a = 0, q = 0;
  for (int j = 0; j < 8; j++) { a += pp[(c * 8 + j) * 2]; q += pp[(c * 8 + j) * 2 + 1]; }
  double mu = a / n;
  double var = q / n - mu * mu;
  float rsig = 1.0f / sqrtf((float)var + 1e-5f);
  float A = gamma[c] * rsig;
  float Bv = beta[c] - (float)mu * A;
  float* cf = (t < 64) ? cf0 : cf1;
  cf[2 * c] = A;
  cf[2 * c + 1] = Bv;
}

// ---- fused finalize + sew-up gather: branchless via code table ----
__global__ __launch_bounds__(256) void final_fused(
    const float* __restrict__ xtr, const float* __restrict__ y10,
    const float* __restrict__ y11, const float* __restrict__ cf0,
    const float* __restrict__ cf1, const int* __restrict__ codes,
    float* __restrict__ out) {
  const int bc = blockIdx.y;
  const int k = blockIdx.x * 256 + threadIdx.x;
  const int c = bc & 63;
  const float A0 = cf0[2 * c], B0 = cf0[2 * c + 1];
  const float A1 = cf1[2 * c], B1 = cf1[2 * c + 1];
  const float* xr  = xtr + (long)bc * TT;
  const float* y0r = y10 + (long)bc * V0v;
  const float* y1r = y11 + (long)bc * V1v;

  int code = codes[k];
  int type = code & 3;
  int xi = (code >> 2) & 4095;
  int yi = code >> 14;
  float xv = xr[xi];
  const float* yrow = (type == 2) ? y1r : y0r;
  float yv = yrow[yi];
  float A = (type == 0) ? 0.f : ((type == 2) ? A1 : A0);
  float Bv = (type == 0) ? 0.f : ((type == 2) ? B1 : B0);
  float z = fmaf(A, yv, Bv);
  float e = (z > 0.f) ? z : (expf(z) - 1.f);
  out[(long)bc * OUTL + k] = xv + e;
}

extern "C" void kernel_launch(void* const* d_in, const int* in_sizes, int n_in,
                              void* d_out, int out_size, void* d_ws, size_t ws_size,
                              hipStream_t stream) {
  const float* x   = (const float*)d_in[0];
  const float* cv  = (const float*)d_in[1];
  const float* cg  = (const float*)d_in[2];
  const float* cb  = (const float*)d_in[3];
  const float* gam = (const float*)d_in[4];
  const float* bet = (const float*)d_in[5];
  float* out = (float*)d_out;

  char* ws = (char*)d_ws;
  size_t cur = 0;
  auto alloc = [&](size_t bytes) -> char* {
    char* p = ws + cur;
    cur = (cur + bytes + 255) & ~(size_t)255;
    return p;
  };
  double* part   = (double*)alloc(4096 * 2 * sizeof(double));
  double* stats  = (double*)alloc(4 * sizeof(double));
  float*  wt     = (float*)alloc(3 * 64 * 64 * sizeof(float));
  double* bnpt0  = (double*)alloc(64 * 8 * 2 * sizeof(double));
  double* bnpt1  = (double*)alloc(64 * 8 * 2 * sizeof(double));
  float*  cf0    = (float*)alloc(128 * sizeof(float));
  float*  cf1    = (float*)alloc(128 * sizeof(float));
  int*    codes  = (int*)alloc(OUTL * sizeof(int));
  float*  xtr    = (float*)alloc((size_t)BB * CC * TT * sizeof(float));
  float*  y10    = (float*)alloc((size_t)4096 * V0v * sizeof(float));
  float*  y11    = (float*)alloc((size_t)4096 * V1v * sizeof(float));

  transpose_stats<<<dim3(64, 64), 256, 0, stream>>>(x, xtr, part);
  stats_final<<<1, 256, 0, stream>>>(part, stats);
  weight_norm<<<64, 256, 0, stream>>>(cv, cg, wt);
  build_codes<<<24, 256, 0, stream>>>(codes);

  conv_pool<<<dim3(64, (V0v + 30) / 31), 256, 0, stream>>>(x, wt, cb, stats, y10, L0v, U0v, V0v, 2, 1);
  conv_pool<<<dim3(64, (V1v + 30) / 31), 256, 0, stream>>>(x, wt, cb, stats, y11, L1v, U1v, V1v, 4, 3);

  bn_partial<<<dim3(64, 8), 256, 0, stream>>>(y10, bnpt0, V0v, 1024);
  bn_partial<<<dim3(64, 8), 256, 0, stream>>>(y11, bnpt1, V1v, 512);
  bn_final<<<1, 128, 0, stream>>>(bnpt0, bnpt1, gam, bet, cf0, cf1);

  final_fused<<<dim3(24, 4096), 256, 0, stream>>>(xtr, y10, y11, cf0, cf1, codes, out);
}